// Round 6
// baseline (760.629 us; speedup 1.0000x reference)
//
#include <hip/hip_runtime.h>
#include <stdint.h>

// D = 4096, TOKENS = (4,2048) -> M = 8192.
#define DD 4096
#define NE_IDX 3277   // round(4096*0.8)

typedef __attribute__((ext_vector_type(8))) short short8;
typedef __attribute__((ext_vector_type(16))) float f32x16;
typedef __attribute__((ext_vector_type(4))) unsigned int u32x4;

__device__ __forceinline__ unsigned short f2bf(float f) {
    unsigned int u = __float_as_uint(f);
    u += 0x7fffu + ((u >> 16) & 1u);
    return (unsigned short)(u >> 16);
}

__device__ __forceinline__ void gload16(const void* g, void* l) {
    __builtin_amdgcn_global_load_lds(
        (const __attribute__((address_space(1))) unsigned int*)g,
        (__attribute__((address_space(3))) unsigned int*)l,
        16, 0, 0);
}

// ---------------------------------------------------------------------------
__global__ void detect_kernel(const unsigned int* __restrict__ k0, int* __restrict__ flag) {
    if (blockIdx.x == 0 && threadIdx.x == 0) {
        int ok4 = 1;
        for (int i = 0; i < 256; ++i) {
            unsigned int v = k0[i];
            if (!(v == 0u || v == 1u || v == 0x3f800000u)) { ok4 = 0; break; }
        }
        *flag = ok4;
    }
}

// ---------------------------------------------------------------------------
__global__ void pack_x_kernel(const float* __restrict__ x, unsigned short* __restrict__ xb, int n8) {
    const int stride = gridDim.x * blockDim.x;
    for (int i = blockIdx.x * blockDim.x + threadIdx.x; i < n8; i += stride) {
        const float4* p = (const float4*)(x + (size_t)i * 8);
        float4 a = p[0], b = p[1];
        short8 r;
        r[0] = (short)f2bf(a.x); r[1] = (short)f2bf(a.y);
        r[2] = (short)f2bf(a.z); r[3] = (short)f2bf(a.w);
        r[4] = (short)f2bf(b.x); r[5] = (short)f2bf(b.y);
        r[6] = (short)f2bf(b.z); r[7] = (short)f2bf(b.w);
        *(short8*)(xb + (size_t)i * 8) = r;
    }
}

// ---------------------------------------------------------------------------
// wt[j*DD + i] = s * (i < ne ? 1 : inh) * (k[i][j] ? 1 : -1), 64x64 LDS transpose
// ---------------------------------------------------------------------------
__global__ void pack_w_kernel(const void* __restrict__ kin, unsigned short* __restrict__ wt,
                              const float* __restrict__ sptr, float inh, int ne,
                              const int* __restrict__ flag) {
    __shared__ unsigned short tile[64][68];
    const int elem4 = *flag;
    const float s = *sptr;
    const int i0 = blockIdx.x * 64;
    const int j0 = blockIdx.y * 64;
    const int t = threadIdx.x;
    {
        const int il = t >> 2;
        const int jc = (t & 3) * 16;
        const int gi = i0 + il;
        const float mag = s * ((gi < ne) ? 1.0f : inh);
        const unsigned short pos = f2bf(mag);
        const unsigned short neg = f2bf(-mag);
        if (elem4) {
            const unsigned int* k32 = (const unsigned int*)kin + (size_t)gi * DD + j0 + jc;
            #pragma unroll
            for (int q = 0; q < 4; ++q) {
                u32x4 v = *(const u32x4*)(k32 + q * 4);
                #pragma unroll
                for (int e = 0; e < 4; ++e)
                    tile[il][jc + q * 4 + e] = v[e] ? pos : neg;
            }
        } else {
            const unsigned char* k8 = (const unsigned char*)kin + (size_t)gi * DD + j0 + jc;
            u32x4 v = *(const u32x4*)k8;
            #pragma unroll
            for (int q = 0; q < 4; ++q) {
                unsigned int w = v[q];
                tile[il][jc + q * 4 + 0] = (w & 0xffu) ? pos : neg;
                tile[il][jc + q * 4 + 1] = ((w >> 8) & 0xffu) ? pos : neg;
                tile[il][jc + q * 4 + 2] = ((w >> 16) & 0xffu) ? pos : neg;
                tile[il][jc + q * 4 + 3] = ((w >> 24) & 0xffu) ? pos : neg;
            }
        }
    }
    __syncthreads();
    {
        const int jl = t >> 2;
        const int ic = (t & 3) * 16;
        short8 o0, o1;
        #pragma unroll
        for (int e = 0; e < 8; ++e) o0[e] = (short)tile[ic + e][jl];
        #pragma unroll
        for (int e = 0; e < 8; ++e) o1[e] = (short)tile[ic + 8 + e][jl];
        unsigned short* dst = wt + (size_t)(j0 + jl) * DD + i0 + ic;
        *(short8*)(dst) = o0;
        *(short8*)(dst + 8) = o1;
    }
}

// ---------------------------------------------------------------------------
// 256x256 tile, BK=64, 8 waves (2Mx4N), 4 phases/K-tile, 32x32x16 MFMA.
// LDS: double-row layout (R5, conflict-free): drow d = rows {2d,2d+1},
// slot = (kc | rbit<<3) ^ (d & 15); staging linear per wave, inverse
// permutation pre-applied to per-lane global source (coalesced 8x128B).
// m201 schedule: per phase {ds_reads ; 1 stage site ; BARRIER ; lgkmcnt(0) ;
// 8 MFMA (setprio) ; [boundary vmcnt] ; BARRIER}. ONE vmcnt(4) per K-tile.
// Stage plan during tile u:  p0: A1(u+1) -> idle buf (free all tile)
//   p1: B0(u+2) -> cur buf (B0 region's last read is p0, freed by p0 end-bar)
//   p2: B1(u+2) (freed p1-end)      p3: A0(u+2) (A0 read only at p0)
// Boundary vmcnt(4) leaves {B1(u+2),A0(u+2)} in flight; everything through
// B0(u+2) landed => tile u+1 complete (A0@u-1.p3, A1@u.p0, B0@u-1.p1,
// B1@u-1.p2 all older). Prologue issues A0,A1,B0,B1(0),B0,B1(1),A0(1) then
// vmcnt(4) = same invariant. Tail: t=62 stages only A1(63), vmcnt(0).
// ---------------------------------------------------------------------------
#define PH32(MH, NH, LA, LB, STAGE_STMT, VM) do {                               \
    if (LA) {                                                                   \
        _Pragma("unroll")                                                       \
        for (int mi = 0; mi < 2; ++mi)                                          \
            _Pragma("unroll")                                                   \
            for (int s = 0; s < 4; ++s)                                         \
                af[mi][s] = *(const short8*)(Lc + (ab2[(MH)*2+mi] ^ (s<<5)));   \
    }                                                                           \
    if (LB) {                                                                   \
        _Pragma("unroll")                                                       \
        for (int s = 0; s < 4; ++s)                                             \
            bf[(NH)][s] = *(const short8*)(Lc + (bb2[(NH)] ^ (s<<5)));          \
    }                                                                           \
    STAGE_STMT;                                                                 \
    __builtin_amdgcn_s_barrier();                                               \
    asm volatile("s_waitcnt lgkmcnt(0)" ::: "memory");                          \
    __builtin_amdgcn_sched_barrier(0);                                          \
    __builtin_amdgcn_s_setprio(1);                                              \
    _Pragma("unroll")                                                           \
    for (int s = 0; s < 4; ++s)                                                 \
        _Pragma("unroll")                                                       \
        for (int mi = 0; mi < 2; ++mi)                                          \
            acc[(MH)*2+mi][(NH)] = __builtin_amdgcn_mfma_f32_32x32x16_bf16(     \
                af[mi][s], bf[(NH)][s], acc[(MH)*2+mi][(NH)], 0, 0, 0);         \
    __builtin_amdgcn_s_setprio(0);                                              \
    __builtin_amdgcn_sched_barrier(0);                                          \
    if ((VM) == 1) asm volatile("s_waitcnt vmcnt(4)" ::: "memory");             \
    if ((VM) == 2) asm volatile("s_waitcnt vmcnt(0)" ::: "memory");             \
    __builtin_amdgcn_s_barrier();                                               \
} while (0)

template <int MODE>
__global__ __launch_bounds__(512, 2)
void gemm256_kernel(const unsigned short* __restrict__ A,   // M x 4096 bf16
                    const unsigned short* __restrict__ Bt,  // 4096 x 4096 bf16 (N x K)
                    void* __restrict__ Cout)
{
    __shared__ unsigned short L[65536];  // 128 KiB: buf0{A,B} buf1{A,B}
    const char* Lc = (const char*)L;

    const int tid  = threadIdx.x;
    const int lane = tid & 63;
    const int l31  = lane & 31;
    const int hb   = lane >> 5;          // k-half select
    const int wave = tid >> 6;
    const int wr   = wave >> 2;    // 0..1
    const int wc   = wave & 3;     // 0..3

    // XCD swizzle (grid = 512, divisible by 8)
    int wg = blockIdx.x;
    const int per = gridDim.x >> 3;
    wg = (wg & 7) * per + (wg >> 3);
    const int tm = wg >> 4;        // 32 M-tiles
    const int tn = wg & 15;        // 16 N-tiles

    const size_t arow0 = (size_t)tm * 256;
    const size_t brow0 = (size_t)tn * 256;

    // --- staging constants (slot involution pre-applied to global source) ---
    const int sx  = (tid & 15) ^ ((tid >> 4) & 15);
    const int kcS = (sx & 7) << 3;                 // k element offset 0..56
    const int rbS = sx >> 3;                       // row parity
    const int arowloc = ((tid >> 4) << 1) + rbS;   // 0..63 within A site
    const int lcl = tid & 255;
    const int seg = tid >> 8;
    const int browloc = ((lcl >> 4) << 1) + rbS;   // 0..31 within B segment

    // A site (c,q): drows [c*32+q*64, +32), global rows c*64+q*128+[0,64)
    auto stageA = [&](int sb, int c, int kt) {
        #pragma unroll
        for (int q = 0; q < 2; ++q) {
            gload16(A + ((arow0 + c * 64 + q * 128 + arowloc) << 12) + kt + kcS,
                    (void*)&L[sb + (c * 32 + q * 64) * 128 + tid * 8]);
        }
    };
    // B site (c,q): drows {c*16+seg*32+q*64}, global cols = drow*2+browloc
    auto stageB = [&](int sb, int c, int kt) {
        #pragma unroll
        for (int q = 0; q < 2; ++q) {
            const int d0 = c * 16 + seg * 32 + q * 64;
            gload16(Bt + ((brow0 + d0 * 2 + browloc) << 12) + kt + kcS,
                    (void*)&L[sb + 16384 + d0 * 128 + lcl * 8]);
        }
    };

    // --- ds_read byte bases (double-row + slot swizzle; step s: XOR s<<5) ---
    const int slot0 = (hb | ((l31 & 1) << 3)) ^ (l31 >> 1);
    int ab2[4], bb2[2];
    #pragma unroll
    for (int mt = 0; mt < 4; ++mt) {
        const int d = wr * 64 + mt * 16 + (l31 >> 1);
        ab2[mt] = (d << 8) + (slot0 << 4);
    }
    #pragma unroll
    for (int nt = 0; nt < 2; ++nt) {
        const int d = wc * 32 + nt * 16 + (l31 >> 1);
        bb2[nt] = 32768 + (d << 8) + (slot0 << 4);
    }

    short8 af[2][4], bf[2][4];
    f32x16 acc[4][2];
    #pragma unroll
    for (int m = 0; m < 4; ++m)
        #pragma unroll
        for (int n = 0; n < 2; ++n)
            #pragma unroll
            for (int e = 0; e < 16; ++e)
                acc[m][n][e] = 0.f;

    // prologue: tile0 (A0,A1,B0,B1) + B0(1),B1(1),A0(1); vmcnt(4) => tile0 +
    // B0(1) landed, {B1(1),A0(1)} in flight  == steady-state entry invariant
    stageA(0, 0, 0); stageA(0, 1, 0); stageB(0, 0, 0); stageB(0, 1, 0);
    stageB(32768, 0, 64); stageB(32768, 1, 64); stageA(32768, 0, 64);
    asm volatile("s_waitcnt vmcnt(4)" ::: "memory");
    __builtin_amdgcn_s_barrier();
    __builtin_amdgcn_sched_barrier(0);

    for (int t = 0; t < 62; ++t) {
        const int sbn = ((t & 1) ^ 1) * 32768;  // idle buf (tile t+1)
        const int sbc = (t & 1) * 32768;        // current buf (tile t+2 dest)
        const int kt1 = (t + 1) * 64;
        const int kt2 = (t + 2) * 64;
        PH32(0, 0, 1, 1, stageA(sbn, 1, kt1), 0);
        PH32(0, 1, 0, 1, stageB(sbc, 0, kt2), 0);
        PH32(1, 1, 1, 0, stageB(sbc, 1, kt2), 0);
        PH32(1, 0, 0, 0, stageA(sbc, 0, kt2), 1);   // boundary vmcnt(4)
        #pragma unroll
        for (int i = 0; i < 4; ++i) ab2[i] ^= 65536;
        bb2[0] ^= 65536; bb2[1] ^= 65536;
    }
    // t=62: only A1(63) remains to stage; boundary drains everything
    PH32(0, 0, 1, 1, stageA(32768, 1, 63 * 64), 0);
    PH32(0, 1, 0, 1, (void)0, 0);
    PH32(1, 1, 1, 0, (void)0, 0);
    PH32(1, 0, 0, 0, (void)0, 2);                   // vmcnt(0)
    #pragma unroll
    for (int i = 0; i < 4; ++i) ab2[i] ^= 65536;
    bb2[0] ^= 65536; bb2[1] ^= 65536;
    // t=63: pure compute from buf1
    PH32(0, 0, 1, 1, (void)0, 0);
    PH32(0, 1, 0, 1, (void)0, 0);
    PH32(1, 1, 1, 0, (void)0, 0);
    PH32(1, 0, 0, 0, (void)0, 0);

    // epilogue: C/D col = lane&31, row = (reg&3) + 8*(reg>>2) + 4*(lane>>5)
    const int orow0 = tm * 256 + wr * 128 + hb * 4;
    const int ocol0 = tn * 256 + wc * 64 + l31;
    #pragma unroll
    for (int mt = 0; mt < 4; ++mt) {
        #pragma unroll
        for (int nt = 0; nt < 2; ++nt) {
            #pragma unroll
            for (int reg = 0; reg < 16; ++reg) {
                const int row = orow0 + mt * 32 + (reg & 3) + 8 * (reg >> 2);
                const int col = ocol0 + nt * 32;
                float v = acc[mt][nt][reg];
                if (MODE == 1) {
                    v = fmaxf(v, 0.0f) * 2.0f;
                    ((unsigned short*)Cout)[((size_t)row << 12) + col] = f2bf(v);
                } else {
                    ((float*)Cout)[((size_t)row << 12) + col] = v;
                }
            }
        }
    }
}

// ---------------------------------------------------------------------------
extern "C" void kernel_launch(void* const* d_in, const int* in_sizes, int n_in,
                              void* d_out, int out_size, void* d_ws, size_t ws_size,
                              hipStream_t stream) {
    const float* x  = (const float*)d_in[0];
    const void*  k0 = d_in[1];
    const float* s0 = (const float*)d_in[2];
    const void*  k1 = d_in[3];
    const float* s1 = (const float*)d_in[4];
    const void*  k2 = d_in[5];
    const float* s2 = (const float*)d_in[6];

    const int M = in_sizes[0] / DD;   // 8192

    const size_t act_bytes = (size_t)M * DD * 2;
    const size_t w_bytes   = (size_t)DD * DD * 2;
    const size_t need      = act_bytes * 2 + w_bytes + 256;
    if (ws_size < need) return;

    char* ws = (char*)d_ws;
    unsigned short* xb = (unsigned short*)ws;                        // M x DD bf16 (later h2)
    unsigned short* h1 = (unsigned short*)(ws + act_bytes);          // M x DD bf16
    unsigned short* wt = (unsigned short*)(ws + act_bytes * 2);      // DD x DD bf16 (N x K)
    int* flag          = (int*)(ws + act_bytes * 2 + w_bytes);

    detect_kernel<<<1, 64, 0, stream>>>((const unsigned int*)k0, flag);
    pack_x_kernel<<<2048, 256, 0, stream>>>(x, xb, M * DD / 8);

    dim3 pw_grid(DD / 64, DD / 64);
    const int gemm_grid = (M / 256) * (DD / 256);   // 512

    // layer 0: h1 = relu(s0 * x @ W0) * 2
    pack_w_kernel<<<pw_grid, 256, 0, stream>>>(k0, wt, s0, 1.0f, DD, flag);
    gemm256_kernel<1><<<gemm_grid, 512, 0, stream>>>(xb, wt, h1);

    // layer 1: h2 = relu(ei_dense(h1, k1, s1)) * 2
    pack_w_kernel<<<pw_grid, 256, 0, stream>>>(k1, wt, s1, -4.0f, NE_IDX, flag);
    gemm256_kernel<1><<<gemm_grid, 512, 0, stream>>>(h1, wt, xb);

    // layer 2: out = ei_dense(h2, k2, s2), fp32
    pack_w_kernel<<<pw_grid, 256, 0, stream>>>(k2, wt, s2, -4.0f, NE_IDX, flag);
    gemm256_kernel<0><<<gemm_grid, 512, 0, stream>>>(xb, wt, (float*)d_out);
}

// Round 7
// 729.627 us; speedup vs baseline: 1.0425x; 1.0425x over previous
//
#include <hip/hip_runtime.h>
#include <stdint.h>

// D = 4096, TOKENS = (4,2048) -> M = 8192.
#define DD 4096
#define NE_IDX 3277   // round(4096*0.8)

typedef __attribute__((ext_vector_type(8))) short short8;
typedef __attribute__((ext_vector_type(16))) float f32x16;
typedef __attribute__((ext_vector_type(4))) unsigned int u32x4;

__device__ __forceinline__ unsigned short f2bf(float f) {
    unsigned int u = __float_as_uint(f);
    u += 0x7fffu + ((u >> 16) & 1u);
    return (unsigned short)(u >> 16);
}

__device__ __forceinline__ void gload16(const void* g, void* l) {
    __builtin_amdgcn_global_load_lds(
        (const __attribute__((address_space(1))) unsigned int*)g,
        (__attribute__((address_space(3))) unsigned int*)l,
        16, 0, 0);
}

#define VMC4 asm volatile("s_waitcnt vmcnt(4)" ::: "memory")
#define VMC2 asm volatile("s_waitcnt vmcnt(2)" ::: "memory")
#define VMC0 asm volatile("s_waitcnt vmcnt(0)" ::: "memory")
#define LGKM do { asm volatile("s_waitcnt lgkmcnt(0)" ::: "memory"); \
                  __builtin_amdgcn_sched_barrier(0); } while (0)
#define BAR  __builtin_amdgcn_s_barrier()

// ---------------------------------------------------------------------------
__global__ void detect_kernel(const unsigned int* __restrict__ k0, int* __restrict__ flag) {
    if (blockIdx.x == 0 && threadIdx.x == 0) {
        int ok4 = 1;
        for (int i = 0; i < 256; ++i) {
            unsigned int v = k0[i];
            if (!(v == 0u || v == 1u || v == 0x3f800000u)) { ok4 = 0; break; }
        }
        *flag = ok4;
    }
}

// ---------------------------------------------------------------------------
__global__ void pack_x_kernel(const float* __restrict__ x, unsigned short* __restrict__ xb, int n8) {
    const int stride = gridDim.x * blockDim.x;
    for (int i = blockIdx.x * blockDim.x + threadIdx.x; i < n8; i += stride) {
        const float4* p = (const float4*)(x + (size_t)i * 8);
        float4 a = p[0], b = p[1];
        short8 r;
        r[0] = (short)f2bf(a.x); r[1] = (short)f2bf(a.y);
        r[2] = (short)f2bf(a.z); r[3] = (short)f2bf(a.w);
        r[4] = (short)f2bf(b.x); r[5] = (short)f2bf(b.y);
        r[6] = (short)f2bf(b.z); r[7] = (short)f2bf(b.w);
        *(short8*)(xb + (size_t)i * 8) = r;
    }
}

// ---------------------------------------------------------------------------
// wt[j*DD + i] = s * (i < ne ? 1 : inh) * (k[i][j] ? 1 : -1), 64x64 LDS transpose
// ---------------------------------------------------------------------------
__global__ void pack_w_kernel(const void* __restrict__ kin, unsigned short* __restrict__ wt,
                              const float* __restrict__ sptr, float inh, int ne,
                              const int* __restrict__ flag) {
    __shared__ unsigned short tile[64][68];
    const int elem4 = *flag;
    const float s = *sptr;
    const int i0 = blockIdx.x * 64;
    const int j0 = blockIdx.y * 64;
    const int t = threadIdx.x;
    {
        const int il = t >> 2;
        const int jc = (t & 3) * 16;
        const int gi = i0 + il;
        const float mag = s * ((gi < ne) ? 1.0f : inh);
        const unsigned short pos = f2bf(mag);
        const unsigned short neg = f2bf(-mag);
        if (elem4) {
            const unsigned int* k32 = (const unsigned int*)kin + (size_t)gi * DD + j0 + jc;
            #pragma unroll
            for (int q = 0; q < 4; ++q) {
                u32x4 v = *(const u32x4*)(k32 + q * 4);
                #pragma unroll
                for (int e = 0; e < 4; ++e)
                    tile[il][jc + q * 4 + e] = v[e] ? pos : neg;
            }
        } else {
            const unsigned char* k8 = (const unsigned char*)kin + (size_t)gi * DD + j0 + jc;
            u32x4 v = *(const u32x4*)k8;
            #pragma unroll
            for (int q = 0; q < 4; ++q) {
                unsigned int w = v[q];
                tile[il][jc + q * 4 + 0] = (w & 0xffu) ? pos : neg;
                tile[il][jc + q * 4 + 1] = ((w >> 8) & 0xffu) ? pos : neg;
                tile[il][jc + q * 4 + 2] = ((w >> 16) & 0xffu) ? pos : neg;
                tile[il][jc + q * 4 + 3] = ((w >> 24) & 0xffu) ? pos : neg;
            }
        }
    }
    __syncthreads();
    {
        const int jl = t >> 2;
        const int ic = (t & 3) * 16;
        short8 o0, o1;
        #pragma unroll
        for (int e = 0; e < 8; ++e) o0[e] = (short)tile[ic + e][jl];
        #pragma unroll
        for (int e = 0; e < 8; ++e) o1[e] = (short)tile[ic + 8 + e][jl];
        unsigned short* dst = wt + (size_t)(j0 + jl) * DD + i0 + ic;
        *(short8*)(dst) = o0;
        *(short8*)(dst + 8) = o1;
    }
}

// ---------------------------------------------------------------------------
// 256x256 tile, BK=64, 8 waves (2Mx4N), 32x32x16 MFMA, double-row LDS layout
// (R5, conflict-free). READ-AHEAD pipeline: each phase's frag reads are for
// the NEXT phase, so lgkmcnt(0) always targets ~1-phase-old reads and the
// ds_reads overlap the previous MFMA burst (LDS pipe || matrix pipe).
// Phase order (0,0),(0,1),(1,0),(1,1); reads: bf1@P0, af1@P1, -@P2,
// {af0,bf0}(t+1)@P3. WAR-safe: af0 written P3/last used P1; bf0 written
// P3/last used P2; af1,bf1 writes vs prior-tile P3 uses (program order).
// Stage A0,B0,B1,A1 of tile t+1 at P0..P3 into idle buffer; vmcnt(4) before
// each barrier. Deadlines: B1(t) landed @P0 (leaves {A1(t),A0'}), A1(t) @P1
// (leaves {A0',B0'}), A0',B0' @P3 (leaves {B1',A1'}). P2 needs no barrier.
// Buffer toggle happens just before P3's next-tile reads.
// ---------------------------------------------------------------------------
template <int MODE>
__global__ __launch_bounds__(512, 2)
void gemm256_kernel(const unsigned short* __restrict__ A,   // M x 4096 bf16
                    const unsigned short* __restrict__ Bt,  // 4096 x 4096 bf16 (N x K)
                    void* __restrict__ Cout)
{
    __shared__ unsigned short L[65536];  // 128 KiB: buf0{A,B} buf1{A,B}
    const char* Lc = (const char*)L;

    const int tid  = threadIdx.x;
    const int lane = tid & 63;
    const int l31  = lane & 31;
    const int hb   = lane >> 5;          // k-half select
    const int wave = tid >> 6;
    const int wr   = wave >> 2;    // 0..1
    const int wc   = wave & 3;     // 0..3

    // XCD swizzle (grid = 512, divisible by 8)
    int wg = blockIdx.x;
    const int per = gridDim.x >> 3;
    wg = (wg & 7) * per + (wg >> 3);
    const int tm = wg >> 4;        // 32 M-tiles
    const int tn = wg & 15;        // 16 N-tiles

    const size_t arow0 = (size_t)tm * 256;
    const size_t brow0 = (size_t)tn * 256;

    // --- staging constants (slot involution pre-applied to global source) ---
    const int sx  = (tid & 15) ^ ((tid >> 4) & 15);
    const int kcS = (sx & 7) << 3;                 // k element offset 0..56
    const int rbS = sx >> 3;                       // row parity
    const int arowloc = ((tid >> 4) << 1) + rbS;   // 0..63 within A site
    const int lcl = tid & 255;
    const int seg = tid >> 8;
    const int browloc = ((lcl >> 4) << 1) + rbS;   // 0..31 within B segment

    // A site (c,q): drows [c*32+q*64, +32), global rows c*64+q*128+[0,64)
    auto stageA = [&](int sb, int c, int kt) {
        #pragma unroll
        for (int q = 0; q < 2; ++q) {
            gload16(A + ((arow0 + c * 64 + q * 128 + arowloc) << 12) + kt + kcS,
                    (void*)&L[sb + (c * 32 + q * 64) * 128 + tid * 8]);
        }
    };
    // B site (c,q): drows {c*16+seg*32+q*64}, global cols = drow*2+browloc
    auto stageB = [&](int sb, int c, int kt) {
        #pragma unroll
        for (int q = 0; q < 2; ++q) {
            const int d0 = c * 16 + seg * 32 + q * 64;
            gload16(Bt + ((brow0 + d0 * 2 + browloc) << 12) + kt + kcS,
                    (void*)&L[sb + 16384 + d0 * 128 + lcl * 8]);
        }
    };

    // --- ds_read byte bases (double-row + slot swizzle; step s: XOR s<<5;
    //     m-tile/n-tile select via +4096 immediates) ---
    const int slot0 = (hb | ((l31 & 1) << 3)) ^ (l31 >> 1);
    int abase = ((wr * 64 + (l31 >> 1)) << 8) + (slot0 << 4);
    int bbase = 32768 + ((wc * 32 + (l31 >> 1)) << 8) + (slot0 << 4);

    short8 af[2][2][4];   // [half][mi][s]
    short8 bf[2][4];      // [half][s]
    f32x16 acc[4][2];
    #pragma unroll
    for (int m = 0; m < 4; ++m)
        #pragma unroll
        for (int n = 0; n < 2; ++n)
            #pragma unroll
            for (int e = 0; e < 16; ++e)
                acc[m][n][e] = 0.f;

    auto RD_A = [&](int h) {
        #pragma unroll
        for (int s = 0; s < 4; ++s)
            #pragma unroll
            for (int mi = 0; mi < 2; ++mi)
                af[h][mi][s] = *(const short8*)(Lc + (abase ^ (s << 5)) + ((h * 2 + mi) << 12));
    };
    auto RD_B = [&](int h) {
        #pragma unroll
        for (int s = 0; s < 4; ++s)
            bf[h][s] = *(const short8*)(Lc + (bbase ^ (s << 5)) + (h << 12));
    };
    auto MM = [&](int ah, int bh) {
        __builtin_amdgcn_s_setprio(1);
        #pragma unroll
        for (int s = 0; s < 4; ++s)
            #pragma unroll
            for (int mi = 0; mi < 2; ++mi)
                acc[ah * 2 + mi][bh] = __builtin_amdgcn_mfma_f32_32x32x16_bf16(
                    af[ah][mi][s], bf[bh][s], acc[ah * 2 + mi][bh], 0, 0, 0);
        __builtin_amdgcn_s_setprio(0);
        __builtin_amdgcn_sched_barrier(0);
    };

    // prologue: tile0 chunks A0,B0,B1,A1 -> buf0; vmcnt(4) => A0,B0 landed;
    // then pre-read F_0(0) = af0+bf0.
    stageA(0, 0, 0); stageB(0, 0, 0); stageB(0, 1, 0); stageA(0, 1, 0);
    VMC4; BAR;
    __builtin_amdgcn_sched_barrier(0);
    RD_A(0); RD_B(0);

    for (int t = 0; t < 63; ++t) {
        const int sb  = ((t + 1) & 1) * 32768;  // idle buffer (tile t+1)
        const int kt2 = (t + 1) * 64;
        // P0: MFMA(0,0); read bf1
        stageA(sb, 0, kt2); VMC4; BAR; LGKM;
        RD_B(1); MM(0, 0);
        // P1: MFMA(0,1); read af1
        stageB(sb, 0, kt2); VMC4; BAR; LGKM;
        RD_A(1); MM(0, 1);
        // P2: MFMA(1,0); no reads, no barrier
        stageB(sb, 1, kt2); LGKM;
        MM(1, 0);
        // P3: MFMA(1,1); read af0,bf0 of tile t+1 (toggle first)
        stageA(sb, 1, kt2); VMC4; BAR; LGKM;
        abase ^= 65536; bbase ^= 65536;
        RD_A(0); RD_B(0); MM(1, 1);
    }
    // tail: tile 63 (bases point at its buffer), no staging
    VMC2; BAR; LGKM;           // B1(63) landed
    RD_B(1); MM(0, 0);
    VMC0; BAR; LGKM;           // A1(63) landed
    RD_A(1); MM(0, 1);
    LGKM; MM(1, 0);
    LGKM; MM(1, 1);

    // epilogue: C/D col = lane&31, row = (reg&3) + 8*(reg>>2) + 4*(lane>>5)
    const int orow0 = tm * 256 + wr * 128 + hb * 4;
    const int ocol0 = tn * 256 + wc * 64 + l31;
    #pragma unroll
    for (int mt = 0; mt < 4; ++mt) {
        #pragma unroll
        for (int nt = 0; nt < 2; ++nt) {
            #pragma unroll
            for (int reg = 0; reg < 16; ++reg) {
                const int row = orow0 + mt * 32 + (reg & 3) + 8 * (reg >> 2);
                const int col = ocol0 + nt * 32;
                float v = acc[mt][nt][reg];
                if (MODE == 1) {
                    v = fmaxf(v, 0.0f) * 2.0f;
                    ((unsigned short*)Cout)[((size_t)row << 12) + col] = f2bf(v);
                } else {
                    ((float*)Cout)[((size_t)row << 12) + col] = v;
                }
            }
        }
    }
}

// ---------------------------------------------------------------------------
extern "C" void kernel_launch(void* const* d_in, const int* in_sizes, int n_in,
                              void* d_out, int out_size, void* d_ws, size_t ws_size,
                              hipStream_t stream) {
    const float* x  = (const float*)d_in[0];
    const void*  k0 = d_in[1];
    const float* s0 = (const float*)d_in[2];
    const void*  k1 = d_in[3];
    const float* s1 = (const float*)d_in[4];
    const void*  k2 = d_in[5];
    const float* s2 = (const float*)d_in[6];

    const int M = in_sizes[0] / DD;   // 8192

    const size_t act_bytes = (size_t)M * DD * 2;
    const size_t w_bytes   = (size_t)DD * DD * 2;
    const size_t need      = act_bytes * 2 + w_bytes + 256;
    if (ws_size < need) return;

    char* ws = (char*)d_ws;
    unsigned short* xb = (unsigned short*)ws;                        // M x DD bf16 (later h2)
    unsigned short* h1 = (unsigned short*)(ws + act_bytes);          // M x DD bf16
    unsigned short* wt = (unsigned short*)(ws + act_bytes * 2);      // DD x DD bf16 (N x K)
    int* flag          = (int*)(ws + act_bytes * 2 + w_bytes);

    detect_kernel<<<1, 64, 0, stream>>>((const unsigned int*)k0, flag);
    pack_x_kernel<<<2048, 256, 0, stream>>>(x, xb, M * DD / 8);

    dim3 pw_grid(DD / 64, DD / 64);
    const int gemm_grid = (M / 256) * (DD / 256);   // 512

    // layer 0: h1 = relu(s0 * x @ W0) * 2
    pack_w_kernel<<<pw_grid, 256, 0, stream>>>(k0, wt, s0, 1.0f, DD, flag);
    gemm256_kernel<1><<<gemm_grid, 512, 0, stream>>>(xb, wt, h1);

    // layer 1: h2 = relu(ei_dense(h1, k1, s1)) * 2
    pack_w_kernel<<<pw_grid, 256, 0, stream>>>(k1, wt, s1, -4.0f, NE_IDX, flag);
    gemm256_kernel<1><<<gemm_grid, 512, 0, stream>>>(h1, wt, xb);

    // layer 2: out = ei_dense(h2, k2, s2), fp32
    pack_w_kernel<<<pw_grid, 256, 0, stream>>>(k2, wt, s2, -4.0f, NE_IDX, flag);
    gemm256_kernel<0><<<gemm_grid, 512, 0, stream>>>(xb, wt, (float*)d_out);
}